// Round 13
// baseline (18.063 us; speedup 1.0000x reference)
//
#include <hip/hip_runtime.h>

#define WAVE 64
#define WPB 8                 // waves per block
#define SPB WPB               // structures per block: 1 per wave
#define BLOCK (WAVE * WPB)    // 512

// Wave-uniform per-structure constants: cell + Gram terms.
struct Pre {
  float c[9];
  float C00, C11, C22;        // |col0|^2, |col1|^2, |col2|^2
  float D01, D02, D12;        // 2 * (col_a . col_b)
};

__device__ __forceinline__ void make_pre(Pre& P) {
  P.C00 = P.c[0]*P.c[0] + P.c[3]*P.c[3] + P.c[6]*P.c[6];
  P.C11 = P.c[1]*P.c[1] + P.c[4]*P.c[4] + P.c[7]*P.c[7];
  P.C22 = P.c[2]*P.c[2] + P.c[5]*P.c[5] + P.c[8]*P.c[8];
  P.D01 = 2.f*(P.c[0]*P.c[1] + P.c[3]*P.c[4] + P.c[6]*P.c[7]);
  P.D02 = 2.f*(P.c[0]*P.c[2] + P.c[3]*P.c[5] + P.c[6]*P.c[8]);
  P.D12 = 2.f*(P.c[1]*P.c[2] + P.c[4]*P.c[5] + P.c[7]*P.c[8]);
}

// argmin over 27 periodic images, Gram-expanded:
// d(i,j,k) = rr - 2i g0 - 2j g1 - 2k g2 + i^2 C00 + j^2 C11 + k^2 C22
//            + ij D01 + ik D02 + jk D12,  r = cell@delta, g_a = r . col_a.
// Packed key (bits&~63)|o6, o6 = (i+1)<<4 | (j+1)<<2 | (k+1): lexicographic
// order preserved -> min-key tie-break == jnp.argmin first-min. 64-ulp tie
// region + expansion rounding ~1e-6 << 7.9e-4 threshold; fmax clamp keeps
// near-zero d nonnegative so uint ordering stays valid.
__device__ __forceinline__ int argmin_o(const Pre& P,
                                        float dd0, float dd1, float dd2) {
  const float r0 = P.c[0]*dd0 + P.c[1]*dd1 + P.c[2]*dd2;
  const float r1 = P.c[3]*dd0 + P.c[4]*dd1 + P.c[5]*dd2;
  const float r2 = P.c[6]*dd0 + P.c[7]*dd1 + P.c[8]*dd2;
  const float rr = r0*r0 + r1*r1 + r2*r2;
  const float g0 = r0*P.c[0] + r1*P.c[3] + r2*P.c[6];
  const float g1 = r0*P.c[1] + r1*P.c[4] + r2*P.c[7];
  const float g2 = r0*P.c[2] + r1*P.c[5] + r2*P.c[8];
  const float Am = fmaf(2.f, g0, P.C00), Ap = fmaf(-2.f, g0, P.C00);
  const float Bm = fmaf(2.f, g1, P.C11), Bp = fmaf(-2.f, g1, P.C11);
  const float Km = fmaf(2.f, g2, P.C22), Kp = fmaf(-2.f, g2, P.C22);
  const float BmpD = Bm + P.D01, BmmD = Bm - P.D01;
  const float BppD = Bp + P.D01, BpmD = Bp - P.D01;
  const float uS = P.D02 + P.D12, uD = P.D02 - P.D12;
  const float basem = rr + Am, basep = rr + Ap;

  unsigned best = 0xFFFFFFFFu;
  auto cell3 = [&](float pij, float u, unsigned ob) {
    const float d0 = fmaxf(pij, 0.f);
    const float dp = fmaxf((pij + Kp) + u, 0.f);
    const float dm = fmaxf((pij + Km) - u, 0.f);
    const unsigned kk0 = (__float_as_uint(d0) & ~63u) | (ob + 1u);
    const unsigned kkp = (__float_as_uint(dp) & ~63u) | (ob + 2u);
    const unsigned kkm = (__float_as_uint(dm) & ~63u) | (ob + 0u);
    best = min(best, min(kk0, min(kkp, kkm)));
  };
  cell3(basem + BmpD, -uS,     0u);        // i=-1 j=-1
  cell3(basem,        -P.D02,  4u);        // i=-1 j=0
  cell3(basem + BpmD, -uD,     8u);        // i=-1 j=+1
  cell3(rr + Bm,      -P.D12, 16u);        // i=0  j=-1
  cell3(rr,            0.f,   20u);        // i=0  j=0
  cell3(rr + Bp,       P.D12, 24u);        // i=0  j=+1
  cell3(basep + BmmD,  uD,    32u);        // i=+1 j=-1
  cell3(basep,         P.D02, 36u);        // i=+1 j=0
  cell3(basep + BppD,  uS,    40u);        // i=+1 j=+1
  return (int)(best & 63u);
}

__device__ __forceinline__ float wave_sum(float v) {
#pragma unroll
  for (int m = 32; m >= 1; m >>= 1) v += __shfl_xor(v, m);
  return v;
}

__device__ __forceinline__ int wave_sum_i(int v) {
#pragma unroll
  for (int m = 32; m >= 1; m >>= 1) v += __shfl_xor(v, m);
  return v;
}

// One structure, delta already in registers (count <= WAVE). s = off - delta.
__device__ __forceinline__ float structure_fast(const Pre& P, bool have, int count,
                                                float dd0, float dd1, float dd2) {
  float s0 = 0.f, s1 = 0.f, s2 = 0.f;
  if (have) {
    const int o = argmin_o(P, dd0, dd1, dd2);
    s0 = (float)(((o >> 4) & 3) - 1) - dd0;
    s1 = (float)(((o >> 2) & 3) - 1) - dd1;
    s2 = (float)((o & 3) - 1) - dd2;
  }
  const float sx = wave_sum(s0), sy = wave_sum(s1), sz = wave_sum(s2);
  const float inv = 1.0f / (float)count;
  const float cx = sx * inv, cy = sy * inv, cz = sz * inv;
  return have ? (fabsf(cx - s0) + fabsf(cy - s1) + fabsf(cz - s2)) : 0.f;
}

// General path (any count): stream atoms, recompute for the |.| pass.
__device__ __forceinline__ float structure_general(const Pre& P,
                                                   const float* __restrict__ x,
                                                   const float* __restrict__ xt,
                                                   int start, int count, int tid) {
  float sumx = 0.f, sumy = 0.f, sumz = 0.f;
  for (int n = start + tid; n < start + count; n += WAVE) {
    const float dd0 = xt[3*n] - x[3*n], dd1 = xt[3*n+1] - x[3*n+1],
                dd2 = xt[3*n+2] - x[3*n+2];
    const int o = argmin_o(P, dd0, dd1, dd2);
    sumx += (float)(((o >> 4) & 3) - 1) - dd0;
    sumy += (float)(((o >> 2) & 3) - 1) - dd1;
    sumz += (float)((o & 3) - 1) - dd2;
  }
  sumx = wave_sum(sumx); sumy = wave_sum(sumy); sumz = wave_sum(sumz);
  const float inv = 1.0f / (float)count;
  const float cx = sumx * inv, cy = sumy * inv, cz = sumz * inv;
  float part = 0.f;
  for (int n = start + tid; n < start + count; n += WAVE) {
    const float dd0 = xt[3*n] - x[3*n], dd1 = xt[3*n+1] - x[3*n+1],
                dd2 = xt[3*n+2] - x[3*n+2];
    const int o = argmin_o(P, dd0, dd1, dd2);
    const float s0 = (float)(((o >> 4) & 3) - 1) - dd0;
    const float s1 = (float)(((o >> 2) & 3) - 1) - dd1;
    const float s2 = (float)((o & 3) - 1) - dd2;
    part += fabsf(cx - s0) + fabsf(cy - s1) + fabsf(cz - s2);
  }
  return part;
}

// Block owns 8 consecutive structures, ONE per wave (2048 blocks -> 64
// waves/CU, two occupancy generations for latency replacement). Speculative
// coord prefetch (addresses from na[0]) overlaps the triangular prefix scan;
// verified per-wave, general-path fallback on mismatch.
__global__ __launch_bounds__(BLOCK, 8) void mdl_main(const float* __restrict__ cell,
                                                     const float* __restrict__ x,
                                                     const float* __restrict__ xt,
                                                     const int* __restrict__ na,
                                                     float* __restrict__ partial,
                                                     int B, int N) {
  __shared__ int ired[WPB];
  __shared__ float wpart[WPB];
  const int wid = __builtin_amdgcn_readfirstlane(threadIdx.x / WAVE);
  const int tid = threadIdx.x % WAVE;
  const int blk = blockIdx.x * SPB;  // multiple of 8

  const int b = blk + wid;
  const bool has = b < B;

  const int na0 = __builtin_amdgcn_readfirstlane(na[0]);
  const bool spec = (na0 > 0) && (na0 <= WAVE) &&
                    ((long)(blk + SPB) * (long)na0 <= (long)N);

  // speculative coord prefetch (delta formed after loads land)
  float x0 = 0, x1 = 0, x2 = 0, t0 = 0, t1 = 0, t2 = 0;
  const int pstart = b * na0;
  if (spec && has && tid < na0) {
    const int n = pstart + tid;
    x0 = x[3*n]; x1 = x[3*n+1]; x2 = x[3*n+2];
    t0 = xt[3*n]; t1 = xt[3*n+1]; t2 = xt[3*n+2];
  }
  Pre P;
#pragma unroll
  for (int i = 0; i < 9; ++i) P.c[i] = has ? cell[9 * b + i] : 0.f;

  // triangular exclusive prefix: base = sum(na[0..blk))
  int s = 0;
  const int nv = blk >> 2;  // exact: blk % 4 == 0
  const int4* na4 = (const int4*)na;
  for (int v = threadIdx.x; v < nv; v += BLOCK) {
    const int4 q = na4[v];
    s += q.x + q.y + q.z + q.w;
  }
  s = wave_sum_i(s);
  if (tid == 0) ired[wid] = s;

  // per-wave: the block's 8 structure sizes + 8-lane inclusive scan
  int nloc = 0;
  if (tid < SPB && blk + tid < B) nloc = na[blk + tid];
  int inc = nloc;
#pragma unroll
  for (int m = 1; m < SPB; m <<= 1) {
    const int u = __shfl_up(inc, m);
    if (tid >= m) inc += u;  // lanes >= 8 hold garbage, never read
  }
  __syncthreads();
  int base = 0;
#pragma unroll
  for (int w = 0; w < WPB; ++w) base += ired[w];

  const int n_w = __shfl(nloc, wid), inc_w = __shfl(inc, wid);
  const int start = __builtin_amdgcn_readfirstlane(base + inc_w - n_w);
  const int count = __builtin_amdgcn_readfirstlane(n_w);

  const bool ok = spec && has && (start == pstart) && (count == na0);
  make_pre(P);

  float part = 0.f;
  if (ok) {
    part = structure_fast(P, tid < count, count, t0 - x0, t1 - x1, t2 - x2);
  } else if (has && count > 0) {
    part = structure_general(P, x, xt, start, count, tid);
  }

  part = wave_sum(part);
  if (tid == 0) wpart[wid] = part;
  __syncthreads();
  if (threadIdx.x == 0) {
    float t = 0.f;
#pragma unroll
    for (int w = 0; w < WPB; ++w) t += wpart[w];
    partial[blockIdx.x] = t;
  }
}

// Sum nparts floats (double accum, float4 loads) -> out = sum / (3*N).
__global__ __launch_bounds__(256) void mdl_final(const float* __restrict__ partial,
                                                 int nparts, float* __restrict__ out,
                                                 int N) {
  __shared__ double wsum[4];
  double s = 0.0;
  const int nv4 = nparts >> 2;
  const float4* p4 = (const float4*)partial;
  for (int i = threadIdx.x; i < nv4; i += 256) {
    const float4 q = p4[i];
    s += (double)q.x + (double)q.y + (double)q.z + (double)q.w;
  }
  for (int i = (nv4 << 2) + threadIdx.x; i < nparts; i += 256)
    s += (double)partial[i];
#pragma unroll
  for (int m = 32; m >= 1; m >>= 1) s += __shfl_xor(s, m);
  if ((threadIdx.x & (WAVE - 1)) == 0) wsum[threadIdx.x / WAVE] = s;
  __syncthreads();
  if (threadIdx.x == 0) {
    double t = 0.0;
#pragma unroll
    for (int w = 0; w < 4; ++w) t += wsum[w];
    out[0] = (float)(t / (3.0 * (double)N));
  }
}

extern "C" void kernel_launch(void* const* d_in, const int* in_sizes, int n_in,
                              void* d_out, int out_size, void* d_ws, size_t ws_size,
                              hipStream_t stream) {
  const float* cell = (const float*)d_in[0];
  const float* x    = (const float*)d_in[1];
  const float* xt   = (const float*)d_in[2];
  const int*   na   = (const int*)d_in[3];
  const int B = in_sizes[3];
  const int N = in_sizes[1] / 3;

  const int nblocks = (B + SPB - 1) / SPB;
  float* partial = (float*)d_ws;  // nblocks floats

  mdl_main<<<nblocks, BLOCK, 0, stream>>>(cell, x, xt, na, partial, B, N);
  mdl_final<<<1, 256, 0, stream>>>(partial, nblocks, (float*)d_out, N);
}

// Round 14
// 16.756 us; speedup vs baseline: 1.0780x; 1.0780x over previous
//
#include <hip/hip_runtime.h>

#define WAVE 64
#define WPB 8                 // waves per block
#define SPB (2 * WPB)         // structures per block (2 per wave, consecutive)
#define BLOCK (WAVE * WPB)    // 512

// Wave-uniform per-structure constants: cell + Gram terms.
struct Pre {
  float c[9];
  float C00, C11, C22;        // |col0|^2, |col1|^2, |col2|^2
  float D01, D02, D12;        // 2 * (col_a . col_b)
};

__device__ __forceinline__ void make_pre(Pre& P) {
  P.C00 = P.c[0]*P.c[0] + P.c[3]*P.c[3] + P.c[6]*P.c[6];
  P.C11 = P.c[1]*P.c[1] + P.c[4]*P.c[4] + P.c[7]*P.c[7];
  P.C22 = P.c[2]*P.c[2] + P.c[5]*P.c[5] + P.c[8]*P.c[8];
  P.D01 = 2.f*(P.c[0]*P.c[1] + P.c[3]*P.c[4] + P.c[6]*P.c[7]);
  P.D02 = 2.f*(P.c[0]*P.c[2] + P.c[3]*P.c[5] + P.c[6]*P.c[8]);
  P.D12 = 2.f*(P.c[1]*P.c[2] + P.c[4]*P.c[5] + P.c[7]*P.c[8]);
}

// argmin over 27 periodic images, Gram-expanded:
// d(i,j,k) = rr - 2i g0 - 2j g1 - 2k g2 + i^2 C00 + j^2 C11 + k^2 C22
//            + ij D01 + ik D02 + jk D12,  r = cell@delta, g_a = r . col_a.
// Packed key (bits&~63)|o6, o6 = (i+1)<<4 | (j+1)<<2 | (k+1): lexicographic
// order preserved -> min-key tie-break == jnp.argmin first-min. 64-ulp tie
// region + expansion rounding ~1e-6 << 7.9e-4 threshold; fmax clamp keeps
// near-zero d nonnegative so uint ordering stays valid.
__device__ __forceinline__ int argmin_o(const Pre& P,
                                        float dd0, float dd1, float dd2) {
  const float r0 = P.c[0]*dd0 + P.c[1]*dd1 + P.c[2]*dd2;
  const float r1 = P.c[3]*dd0 + P.c[4]*dd1 + P.c[5]*dd2;
  const float r2 = P.c[6]*dd0 + P.c[7]*dd1 + P.c[8]*dd2;
  const float rr = r0*r0 + r1*r1 + r2*r2;
  const float g0 = r0*P.c[0] + r1*P.c[3] + r2*P.c[6];
  const float g1 = r0*P.c[1] + r1*P.c[4] + r2*P.c[7];
  const float g2 = r0*P.c[2] + r1*P.c[5] + r2*P.c[8];
  const float Am = fmaf(2.f, g0, P.C00), Ap = fmaf(-2.f, g0, P.C00);
  const float Bm = fmaf(2.f, g1, P.C11), Bp = fmaf(-2.f, g1, P.C11);
  const float Km = fmaf(2.f, g2, P.C22), Kp = fmaf(-2.f, g2, P.C22);
  const float BmpD = Bm + P.D01, BmmD = Bm - P.D01;
  const float BppD = Bp + P.D01, BpmD = Bp - P.D01;
  const float uS = P.D02 + P.D12, uD = P.D02 - P.D12;
  const float basem = rr + Am, basep = rr + Ap;

  unsigned best = 0xFFFFFFFFu;
  auto cell3 = [&](float pij, float u, unsigned ob) {
    const float d0 = fmaxf(pij, 0.f);
    const float dp = fmaxf((pij + Kp) + u, 0.f);
    const float dm = fmaxf((pij + Km) - u, 0.f);
    const unsigned kk0 = (__float_as_uint(d0) & ~63u) | (ob + 1u);
    const unsigned kkp = (__float_as_uint(dp) & ~63u) | (ob + 2u);
    const unsigned kkm = (__float_as_uint(dm) & ~63u) | (ob + 0u);
    best = min(best, min(kk0, min(kkp, kkm)));
  };
  cell3(basem + BmpD, -uS,     0u);        // i=-1 j=-1
  cell3(basem,        -P.D02,  4u);        // i=-1 j=0
  cell3(basem + BpmD, -uD,     8u);        // i=-1 j=+1
  cell3(rr + Bm,      -P.D12, 16u);        // i=0  j=-1
  cell3(rr,            0.f,   20u);        // i=0  j=0
  cell3(rr + Bp,       P.D12, 24u);        // i=0  j=+1
  cell3(basep + BmmD,  uD,    32u);        // i=+1 j=-1
  cell3(basep,         P.D02, 36u);        // i=+1 j=0
  cell3(basep + BppD,  uS,    40u);        // i=+1 j=+1
  return (int)(best & 63u);
}

__device__ __forceinline__ float wave_sum(float v) {
#pragma unroll
  for (int m = 32; m >= 1; m >>= 1) v += __shfl_xor(v, m);
  return v;
}

__device__ __forceinline__ int wave_sum_i(int v) {
#pragma unroll
  for (int m = 32; m >= 1; m >>= 1) v += __shfl_xor(v, m);
  return v;
}

// One structure, delta already in registers (count <= WAVE). s = off - delta.
__device__ __forceinline__ float structure_fast(const Pre& P, bool have, int count,
                                                float dd0, float dd1, float dd2) {
  float s0 = 0.f, s1 = 0.f, s2 = 0.f;
  if (have) {
    const int o = argmin_o(P, dd0, dd1, dd2);
    s0 = (float)(((o >> 4) & 3) - 1) - dd0;
    s1 = (float)(((o >> 2) & 3) - 1) - dd1;
    s2 = (float)((o & 3) - 1) - dd2;
  }
  const float sx = wave_sum(s0), sy = wave_sum(s1), sz = wave_sum(s2);
  const float inv = 1.0f / (float)count;
  const float cx = sx * inv, cy = sy * inv, cz = sz * inv;
  return have ? (fabsf(cx - s0) + fabsf(cy - s1) + fabsf(cz - s2)) : 0.f;
}

// General path (any count): stream atoms, recompute for the |.| pass.
__device__ __forceinline__ float structure_general(const Pre& P,
                                                   const float* __restrict__ x,
                                                   const float* __restrict__ xt,
                                                   int start, int count, int tid) {
  float sumx = 0.f, sumy = 0.f, sumz = 0.f;
  for (int n = start + tid; n < start + count; n += WAVE) {
    const float dd0 = xt[3*n] - x[3*n], dd1 = xt[3*n+1] - x[3*n+1],
                dd2 = xt[3*n+2] - x[3*n+2];
    const int o = argmin_o(P, dd0, dd1, dd2);
    sumx += (float)(((o >> 4) & 3) - 1) - dd0;
    sumy += (float)(((o >> 2) & 3) - 1) - dd1;
    sumz += (float)((o & 3) - 1) - dd2;
  }
  sumx = wave_sum(sumx); sumy = wave_sum(sumy); sumz = wave_sum(sumz);
  const float inv = 1.0f / (float)count;
  const float cx = sumx * inv, cy = sumy * inv, cz = sumz * inv;
  float part = 0.f;
  for (int n = start + tid; n < start + count; n += WAVE) {
    const float dd0 = xt[3*n] - x[3*n], dd1 = xt[3*n+1] - x[3*n+1],
                dd2 = xt[3*n+2] - x[3*n+2];
    const int o = argmin_o(P, dd0, dd1, dd2);
    const float s0 = (float)(((o >> 4) & 3) - 1) - dd0;
    const float s1 = (float)(((o >> 2) & 3) - 1) - dd1;
    const float s2 = (float)((o & 3) - 1) - dd2;
    part += fabsf(cx - s0) + fabsf(cy - s1) + fabsf(cz - s2);
  }
  return part;
}

// Block owns 16 consecutive structures (2/wave). Speculative coord prefetch
// (addresses predicted from na[0]) overlaps the triangular prefix scan;
// verified per-wave, general-path fallback on mismatch.
__global__ __launch_bounds__(BLOCK, 8) void mdl_main(const float* __restrict__ cell,
                                                     const float* __restrict__ x,
                                                     const float* __restrict__ xt,
                                                     const int* __restrict__ na,
                                                     float* __restrict__ partial,
                                                     int B, int N) {
  __shared__ int ired[WPB];
  __shared__ float wpart[WPB];
  const int wid = __builtin_amdgcn_readfirstlane(threadIdx.x / WAVE);
  const int tid = threadIdx.x % WAVE;
  const int blk = blockIdx.x * SPB;  // multiple of 16

  const int bA = blk + 2 * wid;
  const int bB = bA + 1;
  const bool hasA = bA < B;
  const bool hasB = bB < B;

  const int na0 = __builtin_amdgcn_readfirstlane(na[0]);
  const bool spec = (na0 > 0) && (na0 <= WAVE) &&
                    ((long)(blk + SPB) * (long)na0 <= (long)N);

  // speculative coord prefetch (deltas formed after loads land)
  float xA0 = 0, xA1 = 0, xA2 = 0, tA0 = 0, tA1 = 0, tA2 = 0;
  float xB0 = 0, xB1 = 0, xB2 = 0, tB0 = 0, tB1 = 0, tB2 = 0;
  const int pstartA = bA * na0;
  const int pstartB = bB * na0;
  if (spec && hasA && tid < na0) {
    const int n = pstartA + tid;
    xA0 = x[3*n]; xA1 = x[3*n+1]; xA2 = x[3*n+2];
    tA0 = xt[3*n]; tA1 = xt[3*n+1]; tA2 = xt[3*n+2];
  }
  if (spec && hasB && tid < na0) {
    const int n = pstartB + tid;
    xB0 = x[3*n]; xB1 = x[3*n+1]; xB2 = x[3*n+2];
    tB0 = xt[3*n]; tB1 = xt[3*n+1]; tB2 = xt[3*n+2];
  }
  Pre PA, PB;
#pragma unroll
  for (int i = 0; i < 9; ++i) PA.c[i] = hasA ? cell[9 * bA + i] : 0.f;
#pragma unroll
  for (int i = 0; i < 9; ++i) PB.c[i] = hasB ? cell[9 * bB + i] : 0.f;

  // triangular exclusive prefix: base = sum(na[0..blk))
  int s = 0;
  const int nv = blk >> 2;
  const int4* na4 = (const int4*)na;
  for (int v = threadIdx.x; v < nv; v += BLOCK) {
    const int4 q = na4[v];
    s += q.x + q.y + q.z + q.w;
  }
  s = wave_sum_i(s);
  if (tid == 0) ired[wid] = s;

  int nloc = 0;
  if (tid < SPB && blk + tid < B) nloc = na[blk + tid];
  int inc = nloc;
#pragma unroll
  for (int m = 1; m < SPB; m <<= 1) {
    const int u = __shfl_up(inc, m);
    if (tid >= m) inc += u;
  }
  __syncthreads();
  int base = 0;
#pragma unroll
  for (int w = 0; w < WPB; ++w) base += ired[w];

  const int laneA = 2 * wid, laneB = laneA + 1;
  const int nA = __shfl(nloc, laneA), incA = __shfl(inc, laneA);
  const int nB = __shfl(nloc, laneB), incB = __shfl(inc, laneB);
  const int startA = __builtin_amdgcn_readfirstlane(base + incA - nA);
  const int countA = __builtin_amdgcn_readfirstlane(nA);
  const int startB = __builtin_amdgcn_readfirstlane(base + incB - nB);
  const int countB = __builtin_amdgcn_readfirstlane(nB);

  const bool okA = spec && hasA && (startA == pstartA) && (countA == na0);
  const bool okB = spec && hasB && (startB == pstartB) && (countB == na0);

  make_pre(PA);
  make_pre(PB);

  float part = 0.f;
  if (okA) {
    part += structure_fast(PA, tid < countA, countA,
                           tA0 - xA0, tA1 - xA1, tA2 - xA2);
  } else if (hasA && countA > 0) {
    part += structure_general(PA, x, xt, startA, countA, tid);
  }
  if (okB) {
    part += structure_fast(PB, tid < countB, countB,
                           tB0 - xB0, tB1 - xB1, tB2 - xB2);
  } else if (hasB && countB > 0) {
    part += structure_general(PB, x, xt, startB, countB, tid);
  }

  part = wave_sum(part);
  if (tid == 0) wpart[wid] = part;
  __syncthreads();
  if (threadIdx.x == 0) {
    float t = 0.f;
#pragma unroll
    for (int w = 0; w < WPB; ++w) t += wpart[w];
    partial[blockIdx.x] = t;
  }
}

// Sum nparts floats (double accum, float4 loads) -> out = sum / (3*N).
__global__ __launch_bounds__(256) void mdl_final(const float* __restrict__ partial,
                                                 int nparts, float* __restrict__ out,
                                                 int N) {
  __shared__ double wsum[4];
  double s = 0.0;
  const int nv4 = nparts >> 2;
  const float4* p4 = (const float4*)partial;
  for (int i = threadIdx.x; i < nv4; i += 256) {
    const float4 q = p4[i];
    s += (double)q.x + (double)q.y + (double)q.z + (double)q.w;
  }
  for (int i = (nv4 << 2) + threadIdx.x; i < nparts; i += 256)
    s += (double)partial[i];
#pragma unroll
  for (int m = 32; m >= 1; m >>= 1) s += __shfl_xor(s, m);
  if ((threadIdx.x & (WAVE - 1)) == 0) wsum[threadIdx.x / WAVE] = s;
  __syncthreads();
  if (threadIdx.x == 0) {
    double t = 0.0;
#pragma unroll
    for (int w = 0; w < 4; ++w) t += wsum[w];
    out[0] = (float)(t / (3.0 * (double)N));
  }
}

extern "C" void kernel_launch(void* const* d_in, const int* in_sizes, int n_in,
                              void* d_out, int out_size, void* d_ws, size_t ws_size,
                              hipStream_t stream) {
  const float* cell = (const float*)d_in[0];
  const float* x    = (const float*)d_in[1];
  const float* xt   = (const float*)d_in[2];
  const int*   na   = (const int*)d_in[3];
  const int B = in_sizes[3];
  const int N = in_sizes[1] / 3;

  const int nblocks = (B + SPB - 1) / SPB;
  float* partial = (float*)d_ws;  // nblocks floats

  mdl_main<<<nblocks, BLOCK, 0, stream>>>(cell, x, xt, na, partial, B, N);
  mdl_final<<<1, 256, 0, stream>>>(partial, nblocks, (float*)d_out, N);
}